// Round 9
// baseline (201.854 us; speedup 1.0000x reference)
//
#include <hip/hip_runtime.h>

// Model dims (fixed by the problem)
#define TT    128
#define CC    64
#define HH    4
#define SS    16
#define D4    256     // 4*C
#define HID_  256
#define VV    32000
#define NPE_  4
#define RR    256     // B*T
#define LOG2E 1.44269504f

__device__ __forceinline__ float wred_sum(float v) {
#pragma unroll
    for (int off = 32; off; off >>= 1) v += __shfl_xor(v, off, 64);
    return v;
}
__device__ __forceinline__ float wred_max(float v) {
#pragma unroll
    for (int off = 32; off; off >>= 1) v = fmaxf(v, __shfl_xor(v, off, 64));
    return v;
}
__device__ __forceinline__ float sigm(float x) {
    return __builtin_amdgcn_rcpf(1.f + exp2f(-x * LOG2E));
}
__device__ __forceinline__ float sigm2(float t) {   // input pre-scaled by log2e
    return __builtin_amdgcn_rcpf(1.f + exp2f(-t));
}

// ---- row-local K/Q/V projection: s_x1[128] = [pos | ln1(x)] ----
// 1024 threads: kq = tid>>9, h = (tid>>7)&3, d = (tid&127)*2  (2 outputs each)
__device__ __forceinline__ void kqv_row(
    int row, int tid, const float* __restrict__ s_x1,
    const float* __restrict__ attW1, const float* __restrict__ ab1,
    const float* __restrict__ valW,
    float* __restrict__ Kp, float* __restrict__ Qp, float* __restrict__ v) {
    int kq = tid >> 9, h = (tid >> 7) & 3, d = (tid & 127) * 2;
    const float* wb = attW1 + (size_t)(h * D4 + kq * 128) * D4 + d;
    float a0 = 0.f, a1 = 0.f;
#pragma unroll 8
    for (int c = 0; c < 128; ++c) {
        float xc = s_x1[c];
        float2 w = *(const float2*)(wb + c * D4);
        a0 += xc * w.x;
        a1 += xc * w.y;
    }
    if (kq == 0) { a0 += ab1[h * D4 + d]; a1 += ab1[h * D4 + d + 1]; }
    float2 o;
    o.x = a0 * LOG2E;          // pre-scale for sigm2
    o.y = a1 * LOG2E;
    float* dst = (kq ? Qp : Kp) + (size_t)(h * RR + row) * D4 + d;
    *(float2*)dst = o;
    // V: first 64 threads additionally compute 64 outputs (16 s x 4 heads)
    if (tid < 64) {
        int hh = tid >> 4, s = tid & 15;
        float a = 0.f;
        for (int k = 0; k < CC; ++k) a += s_x1[64 + k] * valW[(hh * CC + k) * SS + s];
        v[(hh * RR + row) * SS + s] = a;
    }
}

// ============ init: embed + pos FFNs (all 4) + K/Q/V(0), block = row ============
__global__ void __launch_bounds__(1024, 1) k_init(
    const int* __restrict__ idx, const float* __restrict__ tok,
    const float* __restrict__ pe_tab, const float* __restrict__ peW1,
    const float* __restrict__ peb1, const float* __restrict__ peW2,
    const float* __restrict__ peb2, const float* __restrict__ peg,
    const float* __restrict__ pebb,
    const float* __restrict__ ln1g, const float* __restrict__ ln1b,
    const float* __restrict__ attW1, const float* __restrict__ ab1,
    const float* __restrict__ valW,
    float* __restrict__ x, float* __restrict__ pos,
    float* __restrict__ Kp, float* __restrict__ Qp, float* __restrict__ v) {
    int r = blockIdx.x, tid = threadIdx.x;
    int lane = tid & 63, wv = tid >> 6;
    int t = r & 127;
    __shared__ float s_pe[4][CC], s_h1[4][CC];
    __shared__ float s_x1[128], s_xn[CC];
    if (wv < 4) {
        s_pe[wv][lane] = pe_tab[(wv * TT + t) * CC + lane];
    } else if (wv == 4) {
        float xe = tok[idx[r] * CC + lane];
        x[r * CC + lane] = xe;
        s_xn[lane] = xe;
    }
    __syncthreads();
    if (wv < 4) {
        const float* w1 = peW1 + wv * CC * CC;
        float a = peb1[wv * CC + lane];
        for (int k = 0; k < CC; k++) a += s_pe[wv][k] * w1[k * CC + lane];
        s_h1[wv][lane] = sigm(a);
    }
    __syncthreads();
    if (wv < 4) {
        const float* w2 = peW2 + wv * CC * CC;
        float o = peb2[wv * CC + lane];
        for (int k = 0; k < CC; k++) o += s_h1[wv][k] * w2[k * CC + lane];
        float m = wred_sum(o) * (1.f / CC);
        float d = o - m;
        float var = wred_sum(d * d) * (1.f / CC);
        float pv = d * rsqrtf(var + 1e-5f) * peg[wv * CC + lane] + pebb[wv * CC + lane];
        if (wv > 0) pos[(wv * TT + t) * CC + lane] = pv;   // p=0 consumed now
        else        s_x1[lane] = pv;
    } else if (wv == 4) {
        // LN1 of x0
        float xv = s_xn[lane];
        float m = wred_sum(xv) * (1.f / CC);
        float d = xv - m;
        float var = wred_sum(d * d) * (1.f / CC);
        s_x1[64 + lane] = d * rsqrtf(var + 1e-5f) * ln1g[lane] + ln1b[lane];
    }
    __syncthreads();
    kqv_row(r, tid, s_x1, attW1, ab1, valW, Kp, Qp, v);
}

// ============ fused: attention(p)+post -> x, then K/Q/V(p+1); block = row ======
__global__ void __launch_bounds__(1024, 1) k_fused(
    const float* __restrict__ KpR, const float* __restrict__ QpR,
    const float* __restrict__ vR,
    const float* __restrict__ aw2, const float* __restrict__ ab2,
    float* __restrict__ x,
    const float* __restrict__ projW, const float* __restrict__ projb,
    const float* __restrict__ g2, const float* __restrict__ b2,
    const float* __restrict__ fW1, const float* __restrict__ fb1,
    const float* __restrict__ fW2, const float* __restrict__ fb2,
    const float* __restrict__ g3, const float* __restrict__ b3,
    const float* __restrict__ pos_next,
    const float* __restrict__ ln1g, const float* __restrict__ ln1b,
    const float* __restrict__ attW1, const float* __restrict__ ab1,
    const float* __restrict__ valW,
    float* __restrict__ KpW, float* __restrict__ QpW, float* __restrict__ vW,
    int last) {
    int row = blockIdx.x, tid = threadIdx.x;
    int lane = tid & 63, wv = tid >> 6;
    int h = wv & 3, jg = wv >> 2;
    int bat = row >> 7, i = row & 127, t = row & 127;
    __shared__ __align__(16) float q_s[HH][D4];
    __shared__ __align__(16) float w2_s[HH][D4];
    __shared__ float sc[HH][TT];
    __shared__ float part[HH][16][17];
    __shared__ float o_s[CC], s_x[CC], s_h[HID_], red[4][CC];
    __shared__ float s_xn[CC], s_x1[128];
    for (int e = tid; e < HH * D4; e += 1024) {
        q_s[e >> 8][e & 255] = QpR[((e >> 8) * RR + row) * D4 + (e & 255)];
        w2_s[e >> 8][e & 255] = aw2[e] * 0.125f;     // fold C^-0.5
    }
    __syncthreads();
    // scores: wave (h, jg) handles j = jg, jg+4, ...; lane = d (coalesced)
    {
        float4 qq = *(const float4*)&q_s[h][lane * 4];
        float4 ww = *(const float4*)&w2_s[h][lane * 4];
        float b2s = ab2[h] * 0.125f;
        const float* Kb = KpR + (h * RR + bat * TT) * D4;
        for (int j = jg; j <= i; j += 4) {
            float4 kk = *(const float4*)(Kb + j * D4 + lane * 4);
            float a = sigm2(qq.x + kk.x) * ww.x + sigm2(qq.y + kk.y) * ww.y +
                      sigm2(qq.z + kk.z) * ww.z + sigm2(qq.w + kk.w) * ww.w;
            a = wred_sum(a);
            if (lane == 0) sc[h][j] = a + b2s;
        }
    }
    __syncthreads();
    // softmax: waves 0..3 (wave hh = head hh)
    if (wv < 4) {
        int hh = wv;
        float s0 = (lane <= i) ? sc[hh][lane] : -1e30f;
        float s1 = (lane + 64 <= i) ? sc[hh][lane + 64] : -1e30f;
        float m = wred_max(fmaxf(s0, s1));
        float e0 = (lane <= i) ? __expf(s0 - m) : 0.f;
        float e1 = (lane + 64 <= i) ? __expf(s1 - m) : 0.f;
        float inv = __builtin_amdgcn_rcpf(wred_sum(e0 + e1));
        sc[hh][lane] = e0 * inv;
        sc[hh][lane + 64] = e1 * inv;
    }
    __syncthreads();
    // PV: all 16 waves; wave (h,jg), lane -> (jo, s)
    {
        int jo = lane >> 4, s = lane & 15;
        int jstart = jg * 4 + jo;
        const float* vb = vR + (h * RR + bat * TT) * SS;
        float acc = 0.f;
        for (int j = jstart; j <= i; j += 16) acc += sc[h][j] * vb[j * SS + s];
        part[h][jstart][s] = acc;
    }
    __syncthreads();
    if (tid < CC) {
        int hh = tid >> 4, s = tid & 15;
        float a = 0.f;
#pragma unroll
        for (int k = 0; k < 16; ++k) a += part[hh][k][s];
        o_s[tid] = a;
    }
    __syncthreads();
    // post: proj + residual + LN2 (wave 0)
    float xv = 0.f;
    if (tid < CC) {
        float acc = projb[tid];
        for (int k = 0; k < CC; k++) acc += o_s[k] * projW[k * CC + tid];
        xv = x[row * CC + tid] + acc;
        float m = wred_sum(xv) * (1.f / CC);
        float d = xv - m;
        float var = wred_sum(d * d) * (1.f / CC);
        s_x[tid] = d * rsqrtf(var + 1e-5f) * g2[tid] + b2[tid];
    }
    __syncthreads();
    if (tid < 256) {
        float a = fb1[tid];
        for (int k = 0; k < CC; k++) a += s_x[k] * fW1[k * HID_ + tid];
        s_h[tid] = sigm(a);
    }
    __syncthreads();
    if (tid < 256) {
        int c = tid & 63, q = tid >> 6;
        float acc = 0.f;
        for (int k = q * 64; k < q * 64 + 64; ++k) acc += s_h[k] * fW2[k * CC + c];
        red[q][c] = acc;
    }
    __syncthreads();
    if (tid < CC) {
        float f = fb2[tid] + red[0][tid] + red[1][tid] + red[2][tid] + red[3][tid];
        float x2 = xv + f;
        float m = wred_sum(x2) * (1.f / CC);
        float d = x2 - m;
        float var = wred_sum(d * d) * (1.f / CC);
        float xnew = d * rsqrtf(var + 1e-5f) * g3[tid] + b3[tid];
        x[row * CC + tid] = xnew;
        s_xn[tid] = xnew;
    }
    if (last) return;
    // ---- A-part: K/Q/V(p+1) from fresh x (row-local) ----
    __syncthreads();
    if (tid < 64) {
        float xv2 = s_xn[tid];
        float m = wred_sum(xv2) * (1.f / CC);
        float d = xv2 - m;
        float var = wred_sum(d * d) * (1.f / CC);
        s_x1[64 + tid] = d * rsqrtf(var + 1e-5f) * ln1g[tid] + ln1b[tid];
    } else if (tid < 128) {
        s_x1[tid - 64] = pos_next[t * CC + (tid - 64)];
    }
    __syncthreads();
    kqv_row(row, tid, s_x1, attW1, ab1, valW, KpW, QpW, vW);
}

// ============ lm_head: c-outer register GEMM ============
// grid (125, 4); block = 256 cols x 64 rows; thread = 2 cols x 32 rows
__global__ void __launch_bounds__(256, 4) k_lmhead(const float* __restrict__ x,
                                                   const float* __restrict__ lmW,
                                                   const float* __restrict__ lmb,
                                                   float* __restrict__ out) {
    int tid = threadIdx.x;
    int cp = tid & 127, rg = tid >> 7;
    int v2 = blockIdx.x * 256 + cp * 2;
    int r0 = blockIdx.y * 64;
    int rbase = rg * 32;
    __shared__ float xT[CC][68];            // transposed x tile, padded
    for (int e = tid; e < 64 * CC; e += 256) {
        int r = e >> 6, c = e & 63;
        xT[c][r] = x[(r0 + r) * CC + c];
    }
    __syncthreads();
    float2 bias = *(const float2*)(lmb + v2);
    float2 acc[32];
#pragma unroll
    for (int rr = 0; rr < 32; rr++) acc[rr] = bias;
    for (int c = 0; c < CC; ++c) {
        float2 w = *(const float2*)(lmW + (size_t)c * VV + v2);
#pragma unroll
        for (int q = 0; q < 8; ++q) {
            float4 xr = *(const float4*)&xT[c][rbase + q * 4];
            acc[q * 4 + 0].x += xr.x * w.x; acc[q * 4 + 0].y += xr.x * w.y;
            acc[q * 4 + 1].x += xr.y * w.x; acc[q * 4 + 1].y += xr.y * w.y;
            acc[q * 4 + 2].x += xr.z * w.x; acc[q * 4 + 2].y += xr.z * w.y;
            acc[q * 4 + 3].x += xr.w * w.x; acc[q * 4 + 3].y += xr.w * w.y;
        }
    }
#pragma unroll
    for (int rr = 0; rr < 32; rr++)
        *(float2*)(out + (size_t)(r0 + rbase + rr) * VV + v2) = acc[rr];
}

extern "C" void kernel_launch(void* const* d_in, const int* in_sizes, int n_in,
                              void* d_out, int out_size, void* d_ws, size_t ws_size,
                              hipStream_t stream) {
    const int*   idx   = (const int*)d_in[0];
    const float* tok   = (const float*)d_in[1];
    const float* petab = (const float*)d_in[2];
    const float* peW1  = (const float*)d_in[3];
    const float* peb1  = (const float*)d_in[4];
    const float* peW2  = (const float*)d_in[5];
    const float* peb2  = (const float*)d_in[6];
    const float* peg   = (const float*)d_in[7];
    const float* pebb  = (const float*)d_in[8];
    const float* ln1g  = (const float*)d_in[9];
    const float* ln1b  = (const float*)d_in[10];
    const float* attW1 = (const float*)d_in[11];
    const float* attb1 = (const float*)d_in[12];
    const float* attW2 = (const float*)d_in[13];
    const float* attb2 = (const float*)d_in[14];
    const float* valW  = (const float*)d_in[15];
    const float* projW = (const float*)d_in[16];
    const float* projb = (const float*)d_in[17];
    const float* ln2g  = (const float*)d_in[18];
    const float* ln2b  = (const float*)d_in[19];
    const float* ffW1  = (const float*)d_in[20];
    const float* ffb1  = (const float*)d_in[21];
    const float* ffW2  = (const float*)d_in[22];
    const float* ffb2  = (const float*)d_in[23];
    const float* ln3g  = (const float*)d_in[24];
    const float* ln3b  = (const float*)d_in[25];
    const float* lmW   = (const float*)d_in[26];
    const float* lmb   = (const float*)d_in[27];

    float* ws  = (float*)d_ws;
    float* x   = ws;                   // 16384
    float* pos = ws + 16384;           // 32768
    float* v0  = ws + 49152;           // 16384
    float* v1  = ws + 65536;           // 16384
    float* Kp0 = ws + 81920;           // 262144
    float* Qp0 = ws + 344064;          // 262144
    float* Kp1 = ws + 606208;          // 262144
    float* Qp1 = ws + 868352;          // 262144

    k_init<<<RR, 1024, 0, stream>>>(idx, tok, petab, peW1, peb1, peW2, peb2,
                                    peg, pebb, ln1g, ln1b, attW1, attb1, valW,
                                    x, pos, Kp0, Qp0, v0);
    for (int p = 0; p < NPE_; p++) {
        float* KpR = (p & 1) ? Kp1 : Kp0;
        float* QpR = (p & 1) ? Qp1 : Qp0;
        float* vR  = (p & 1) ? v1  : v0;
        float* KpW = (p & 1) ? Kp0 : Kp1;
        float* QpW = (p & 1) ? Qp0 : Qp1;
        float* vW  = (p & 1) ? v0  : v1;
        k_fused<<<RR, 1024, 0, stream>>>(KpR, QpR, vR, attW2, attb2, x,
                                         projW, projb, ln2g, ln2b, ffW1, ffb1,
                                         ffW2, ffb2, ln3g, ln3b,
                                         pos + ((p + 1) & 3) * TT * CC,
                                         ln1g, ln1b, attW1, attb1, valW,
                                         KpW, QpW, vW, (p == NPE_ - 1) ? 1 : 0);
    }
    k_lmhead<<<dim3(125, 4), 256, 0, stream>>>(x, lmW, lmb, (float*)d_out);
}

// Round 10
// 169.264 us; speedup vs baseline: 1.1925x; 1.1925x over previous
//
#include <hip/hip_runtime.h>

// Model dims (fixed by the problem)
#define TT    128
#define CC    64
#define HH    4
#define SS    16
#define D4    256     // 4*C
#define HID_  256
#define VV    32000
#define NPE_  4
#define RR    256     // B*T
#define LOG2E 1.44269504f

__device__ __forceinline__ float wred_sum(float v) {
#pragma unroll
    for (int off = 32; off; off >>= 1) v += __shfl_xor(v, off, 64);
    return v;
}
__device__ __forceinline__ float wred_max(float v) {
#pragma unroll
    for (int off = 32; off; off >>= 1) v = fmaxf(v, __shfl_xor(v, off, 64));
    return v;
}
__device__ __forceinline__ float sigm(float x) {
    return __builtin_amdgcn_rcpf(1.f + exp2f(-x * LOG2E));
}
__device__ __forceinline__ float sigm2(float t) {   // input pre-scaled by log2e
    return __builtin_amdgcn_rcpf(1.f + exp2f(-t));
}

// ============ embed + all positional embeddings (one launch) ============
__global__ void k_embed_pos(const int* __restrict__ idx, const float* __restrict__ tok,
                            const float* __restrict__ pe_tab, const float* __restrict__ W1,
                            const float* __restrict__ b1, const float* __restrict__ W2,
                            const float* __restrict__ b2, const float* __restrict__ g,
                            const float* __restrict__ bb,
                            float* __restrict__ x, float* __restrict__ pos) {
    int blk = blockIdx.x, c = threadIdx.x;
    if (blk >= 512) {
        int r = blk - 512;
        x[r * CC + c] = tok[idx[r] * CC + c];
        return;
    }
    int p = blk >> 7, t = blk & 127;
    __shared__ float s_pe[CC], s_h[CC];
    s_pe[c] = pe_tab[(p * TT + t) * CC + c];
    __syncthreads();
    const float* w1 = W1 + p * CC * CC;
    float a = b1[p * CC + c];
    for (int k = 0; k < CC; k++) a += s_pe[k] * w1[k * CC + c];
    s_h[c] = sigm(a);
    __syncthreads();
    const float* w2 = W2 + p * CC * CC;
    float o = b2[p * CC + c];
    for (int k = 0; k < CC; k++) o += s_h[k] * w2[k * CC + c];
    float m = wred_sum(o) * (1.f / CC);
    float d = o - m;
    float var = wred_sum(d * d) * (1.f / CC);
    pos[(p * TT + t) * CC + c] =
        d * rsqrtf(var + 1e-5f) * g[p * CC + c] + bb[p * CC + c];
}

// ============ stage A: LN1 + K/Q proj (+V on kq==0 blocks) ============
// 256 blocks: rg = blk&31 (8 rows), kq = (blk>>5)&1, h = blk>>6
__global__ void __launch_bounds__(256) k_stageA(
    const float* __restrict__ x, const float* __restrict__ pos_p,
    const float* __restrict__ ln1g, const float* __restrict__ ln1b,
    const float* __restrict__ attW1, const float* __restrict__ ab1,
    const float* __restrict__ valW,
    float* __restrict__ Kp, float* __restrict__ Qp, float* __restrict__ v) {
    int blk = blockIdx.x, tid = threadIdx.x;
    int lane = tid & 63, wv = tid >> 6;
    int rg = blk & 31, kq = (blk >> 5) & 1, h = blk >> 6;
    int r0 = rg * 8;
    __shared__ float x1[8][128];
#pragma unroll
    for (int pass = 0; pass < 2; ++pass) {
        int rr = wv + pass * 4;
        float xv = x[(r0 + rr) * CC + lane];
        float m = wred_sum(xv) * (1.f / CC);
        float d = xv - m;
        float var = wred_sum(d * d) * (1.f / CC);
        x1[rr][64 + lane] = d * rsqrtf(var + 1e-5f) * ln1g[lane] + ln1b[lane];
    }
    for (int e = tid; e < 512; e += 256) {
        int rr = e >> 6, cc = e & 63;
        int t = (r0 + rr) & (TT - 1);
        x1[rr][cc] = pos_p[t * CC + cc];
    }
    __syncthreads();
    const float* w = attW1 + (h * D4 + kq * 128) * D4;
    float acc[8] = {0, 0, 0, 0, 0, 0, 0, 0};
    for (int c = 0; c < 128; c++) {
        float wvv = w[c * D4 + tid];
#pragma unroll
        for (int rr = 0; rr < 8; rr++) acc[rr] += x1[rr][c] * wvv;
    }
    float badd = kq ? 0.f : ab1[h * D4 + tid];   // fold b1 into K
    float* outKQ = kq ? Qp : Kp;
#pragma unroll
    for (int rr = 0; rr < 8; rr++)               // pre-scale by log2e
        outKQ[(h * RR + r0 + rr) * D4 + tid] = (acc[rr] + badd) * LOG2E;
    if (kq == 0 && tid < 128) {
        int rr = tid >> 4, s = tid & 15;
        const float* wvw = valW + h * CC * SS;
        float a = 0.f;
        for (int k = 0; k < CC; k++) a += x1[rr][64 + k] * wvw[k * SS + s];
        v[(h * RR + r0 + rr) * SS + s] = a;
    }
}

// ============ attention: block = (row, head), 1024 blocks x 256 thr ============
__global__ void __launch_bounds__(256) k_attn(
    const float* __restrict__ Kp, const float* __restrict__ Qp,
    const float* __restrict__ v,
    const float* __restrict__ aw2, const float* __restrict__ ab2,
    float* __restrict__ o) {
    int bid = blockIdx.x;
    int row = bid & 255, h = bid >> 8;
    int bat = row >> 7, i = row & 127;
    int tid = threadIdx.x, lane = tid & 63, jg = tid >> 6;
    __shared__ __align__(16) float q_s[D4], w2_s[D4];
    __shared__ float sc[TT];
    __shared__ float part[16][17];
    for (int e = tid; e < D4; e += 256) {
        q_s[e] = Qp[(h * RR + row) * D4 + e];
        w2_s[e] = aw2[h * D4 + e] * 0.125f;          // fold C^-0.5
    }
    __syncthreads();
    float4 qq = *(const float4*)&q_s[lane * 4];
    float4 ww = *(const float4*)&w2_s[lane * 4];
    float b2s = ab2[h] * 0.125f;
    const float* Kb = Kp + (h * RR + bat * TT) * D4;
    // scores: wave jg covers j = jg + 4k; 8 j's per batch for ILP
    for (int jb = jg; jb <= i; jb += 32) {
        float4 kk[8];
#pragma unroll
        for (int u = 0; u < 8; ++u) {
            int j = jb + 4 * u;
            int jc = (j <= i) ? j : i;               // clamp (masked on store)
            kk[u] = *(const float4*)(Kb + jc * D4 + lane * 4);
        }
        float p[8];
#pragma unroll
        for (int u = 0; u < 8; ++u)
            p[u] = sigm2(qq.x + kk[u].x) * ww.x + sigm2(qq.y + kk[u].y) * ww.y +
                   sigm2(qq.z + kk[u].z) * ww.z + sigm2(qq.w + kk[u].w) * ww.w;
#pragma unroll
        for (int off = 32; off; off >>= 1) {
#pragma unroll
            for (int u = 0; u < 8; ++u) p[u] += __shfl_xor(p[u], off, 64);
        }
        if (lane == 0) {
#pragma unroll
            for (int u = 0; u < 8; ++u) {
                int j = jb + 4 * u;
                if (j <= i) sc[j] = p[u] + b2s;
            }
        }
    }
    __syncthreads();
    if (jg == 0) {                                   // softmax, wave 0
        float s0 = (lane <= i) ? sc[lane] : -1e30f;
        float s1 = (lane + 64 <= i) ? sc[lane + 64] : -1e30f;
        float m = wred_max(fmaxf(s0, s1));
        float e0 = (lane <= i) ? __expf(s0 - m) : 0.f;
        float e1 = (lane + 64 <= i) ? __expf(s1 - m) : 0.f;
        float inv = __builtin_amdgcn_rcpf(wred_sum(e0 + e1));
        sc[lane] = e0 * inv;
        sc[lane + 64] = e1 * inv;
    }
    __syncthreads();
    {   // PV: wave jg, lane -> (jo, s); 16 j-strides x 16 s
        int jo = lane >> 4, s = lane & 15;
        int jstart = jg * 4 + jo;
        const float* vb = v + (h * RR + bat * TT) * SS;
        float acc = 0.f;
        for (int j = jstart; j <= i; j += 16) acc += sc[j] * vb[j * SS + s];
        part[jstart][s] = acc;
    }
    __syncthreads();
    if (tid < 16) {
        float a = 0.f;
#pragma unroll
        for (int k = 0; k < 16; ++k) a += part[k][tid];
        o[row * CC + h * SS + tid] = a;
    }
}

// ============ post: proj + residual + LN2 + FF + residual + LN3 ============
__global__ void __launch_bounds__(256) k_post(
    float* __restrict__ x, const float* __restrict__ o,
    const float* __restrict__ projW, const float* __restrict__ projb,
    const float* __restrict__ g2, const float* __restrict__ b2,
    const float* __restrict__ fW1, const float* __restrict__ fb1,
    const float* __restrict__ fW2, const float* __restrict__ fb2,
    const float* __restrict__ g3, const float* __restrict__ b3) {
    int row = blockIdx.x, tid = threadIdx.x;
    __shared__ float o_s[CC], s_x[CC], s_h[HID_], red[4][CC];
    if (tid < CC) o_s[tid] = o[row * CC + tid];
    __syncthreads();
    {   // proj: 4-way k-split, 2 accumulators
        int c = tid & 63, q = tid >> 6;
        float a0 = 0.f, a1 = 0.f;
        int k0 = q * 16;
#pragma unroll
        for (int k = 0; k < 16; k += 2) {
            a0 += o_s[k0 + k] * projW[(k0 + k) * CC + c];
            a1 += o_s[k0 + k + 1] * projW[(k0 + k + 1) * CC + c];
        }
        red[q][c] = a0 + a1;
    }
    __syncthreads();
    float xv = 0.f;
    if (tid < CC) {
        xv = x[row * CC + tid] + projb[tid] +
             red[0][tid] + red[1][tid] + red[2][tid] + red[3][tid];
        float m = wred_sum(xv) * (1.f / CC);
        float d = xv - m;
        float var = wred_sum(d * d) * (1.f / CC);
        s_x[tid] = d * rsqrtf(var + 1e-5f) * g2[tid] + b2[tid];
    }
    __syncthreads();
    {   // FF1: 256 hidden units, 2 accumulators
        float a0 = fb1[tid], a1 = 0.f;
#pragma unroll
        for (int k = 0; k < CC; k += 2) {
            a0 += s_x[k] * fW1[k * HID_ + tid];
            a1 += s_x[k + 1] * fW1[(k + 1) * HID_ + tid];
        }
        s_h[tid] = sigm(a0 + a1);
    }
    __syncthreads();
    {   // FF2: 4-way k-split, 2 accumulators
        int c = tid & 63, q = tid >> 6;
        float a0 = 0.f, a1 = 0.f;
#pragma unroll
        for (int k = q * 64; k < q * 64 + 64; k += 2) {
            a0 += s_h[k] * fW2[k * CC + c];
            a1 += s_h[k + 1] * fW2[(k + 1) * CC + c];
        }
        red[q][c] = a0 + a1;
    }
    __syncthreads();
    if (tid < CC) {
        float f = fb2[tid] + red[0][tid] + red[1][tid] + red[2][tid] + red[3][tid];
        float x2 = xv + f;
        float m = wred_sum(x2) * (1.f / CC);
        float d = x2 - m;
        float var = wred_sum(d * d) * (1.f / CC);
        x[row * CC + tid] = d * rsqrtf(var + 1e-5f) * g3[tid] + b3[tid];
    }
}

// ============ lm_head: c-outer register GEMM ============
__global__ void __launch_bounds__(256, 4) k_lmhead(const float* __restrict__ x,
                                                   const float* __restrict__ lmW,
                                                   const float* __restrict__ lmb,
                                                   float* __restrict__ out) {
    int tid = threadIdx.x;
    int cp = tid & 127, rg = tid >> 7;
    int v2 = blockIdx.x * 256 + cp * 2;
    int r0 = blockIdx.y * 64;
    int rbase = rg * 32;
    __shared__ float xT[CC][68];            // transposed x tile, padded
    for (int e = tid; e < 64 * CC; e += 256) {
        int r = e >> 6, c = e & 63;
        xT[c][r] = x[(r0 + r) * CC + c];
    }
    __syncthreads();
    float2 bias = *(const float2*)(lmb + v2);
    float2 acc[32];
#pragma unroll
    for (int rr = 0; rr < 32; rr++) acc[rr] = bias;
    for (int c = 0; c < CC; ++c) {
        float2 w = *(const float2*)(lmW + (size_t)c * VV + v2);
#pragma unroll
        for (int q = 0; q < 8; ++q) {
            float4 xr = *(const float4*)&xT[c][rbase + q * 4];
            acc[q * 4 + 0].x += xr.x * w.x; acc[q * 4 + 0].y += xr.x * w.y;
            acc[q * 4 + 1].x += xr.y * w.x; acc[q * 4 + 1].y += xr.y * w.y;
            acc[q * 4 + 2].x += xr.z * w.x; acc[q * 4 + 2].y += xr.z * w.y;
            acc[q * 4 + 3].x += xr.w * w.x; acc[q * 4 + 3].y += xr.w * w.y;
        }
    }
#pragma unroll
    for (int rr = 0; rr < 32; rr++)
        *(float2*)(out + (size_t)(r0 + rbase + rr) * VV + v2) = acc[rr];
}

extern "C" void kernel_launch(void* const* d_in, const int* in_sizes, int n_in,
                              void* d_out, int out_size, void* d_ws, size_t ws_size,
                              hipStream_t stream) {
    const int*   idx   = (const int*)d_in[0];
    const float* tok   = (const float*)d_in[1];
    const float* petab = (const float*)d_in[2];
    const float* peW1  = (const float*)d_in[3];
    const float* peb1  = (const float*)d_in[4];
    const float* peW2  = (const float*)d_in[5];
    const float* peb2  = (const float*)d_in[6];
    const float* peg   = (const float*)d_in[7];
    const float* pebb  = (const float*)d_in[8];
    const float* ln1g  = (const float*)d_in[9];
    const float* ln1b  = (const float*)d_in[10];
    const float* attW1 = (const float*)d_in[11];
    const float* attb1 = (const float*)d_in[12];
    const float* attW2 = (const float*)d_in[13];
    const float* attb2 = (const float*)d_in[14];
    const float* valW  = (const float*)d_in[15];
    const float* projW = (const float*)d_in[16];
    const float* projb = (const float*)d_in[17];
    const float* ln2g  = (const float*)d_in[18];
    const float* ln2b  = (const float*)d_in[19];
    const float* ffW1  = (const float*)d_in[20];
    const float* ffb1  = (const float*)d_in[21];
    const float* ffW2  = (const float*)d_in[22];
    const float* ffb2  = (const float*)d_in[23];
    const float* ln3g  = (const float*)d_in[24];
    const float* ln3b  = (const float*)d_in[25];
    const float* lmW   = (const float*)d_in[26];
    const float* lmb   = (const float*)d_in[27];

    float* ws  = (float*)d_ws;
    float* x   = ws;                  // 16384
    float* pos = ws + 16384;          // 32768
    float* v   = ws + 49152;          // 16384
    float* o   = ws + 65536;          // 16384
    float* Kp  = ws + 81920;          // 262144 (pre-scaled, +b1)
    float* Qp  = ws + 344064;         // 262144 (pre-scaled)

    k_embed_pos<<<768, CC, 0, stream>>>(idx, tok, petab, peW1, peb1, peW2, peb2,
                                        peg, pebb, x, pos);
    for (int p = 0; p < NPE_; p++) {
        k_stageA<<<256, 256, 0, stream>>>(x, pos + p * TT * CC, ln1g, ln1b,
                                          attW1, attb1, valW, Kp, Qp, v);
        k_attn<<<HH * RR, 256, 0, stream>>>(Kp, Qp, v, attW2, attb2, o);
        k_post<<<RR, 256, 0, stream>>>(x, o, projW, projb, ln2g, ln2b,
                                       ffW1, ffb1, ffW2, ffb2, ln3g, ln3b);
    }
    k_lmhead<<<dim3(125, 4), 256, 0, stream>>>(x, lmW, lmb, (float*)d_out);
}